// Round 7
// baseline (342.801 us; speedup 1.0000x reference)
//
#include <hip/hip_runtime.h>

// EdgeModel: out = relu(cat[src(64),dest(64),edge(32)] @ w1[160,128] + b1) @ w2[128,32] + b2
// E = 1,600,000 rows, f32 in/out, bf16 MFMA (threshold 8.8e-2 >> ~3e-2 bf16 err).
//
// R7: R6 was LDS-pipe + HBM bound with poor overlap; dominant LDS term = full
// 40KB w1s re-read per wave per 16 rows. Fix: 32 rows per wave-iteration (two
// row-frags; each w1-frag ds_read feeds TWO MFMAs -> w1 LDS traffic halved per
// row), with the 16-row x-buffer TIME-SHARED: issue all 20 global loads
// back-to-back, vmcnt(10) -> stage rows 0-15 -> a0 frags to regs -> vmcnt(0)
// -> restage rows 16-31 into the same buffer -> a1 frags. The waitcnts live in
// asm blocks with "+v"-tied operands so consumers are dataflow-ordered after
// the wait (rule-18-safe). DS ops are wave-in-order and same-object aliased ->
// read-before-rewrite is preserved. LDS stays 145,920 B, 16 waves/CU.
// All math/layouts (w1s staging, swapped GEMM1, slot-bijection GEMM2, f32x4
// stores) are R5/R6-verified.

typedef float  f32x4  __attribute__((ext_vector_type(4)));
typedef short  s16x8  __attribute__((ext_vector_type(8)));
typedef unsigned short u16x4 __attribute__((ext_vector_type(4)));

#define SRC_STRIDE 144               // LDS bytes per 64-col bf16 row (128 + 16 pad)
#define EDG_STRIDE 80                // LDS bytes per 32-col bf16 row (64 + 16 pad)
#define WS_BYTES   (32 * SRC_STRIDE + 16 * EDG_STRIDE)   // 5888 B per wave (16 rows)

__device__ __forceinline__ unsigned short f2bf(float f) {
    // RTNE float -> bf16 bits
    unsigned int u = __float_as_uint(f);
    u += 0x7FFFu + ((u >> 16) & 1u);
    return (unsigned short)(u >> 16);
}

__global__ __launch_bounds__(1024, 1) void edge_mlp(
    const float* __restrict__ src, const float* __restrict__ dst,
    const float* __restrict__ edg, const float* __restrict__ w1,
    const float* __restrict__ b1, const float* __restrict__ w2,
    const float* __restrict__ b2, float* __restrict__ out, int ntiles)
{
    // LDS: w1s 40960 + b1s 512 + w2s 8192 + b2s 2048 + xs 16*5888 = 145,920 B
    // -> 1 block/CU, 16 waves/CU (4 waves/SIMD).
    __shared__ __align__(16) unsigned short w1s[40 * 64 * 8];
    __shared__ __align__(16) float b1s[128];
    __shared__ __align__(16) unsigned short w2s[8 * 64 * 8];   // frag (m,n2) at ((m*2+n2)*64+lane)*8
    __shared__ __align__(16) float b2s[2 * 64 * 4];            // f32x4 per lane per n2
    __shared__ __align__(16) char xs[16][WS_BYTES];

    const int t    = threadIdx.x;
    const int lane = t & 63;
    const int wid  = t >> 6;      // 0..15
    const int rq   = lane >> 4;   // 0..3
    const int rr   = lane & 15;   // 0..15

    // ---- stage w1 into fragment-order LDS (R5/R6-verified layout) ----
    for (int s = t; s < 40 * 64; s += 1024) {
        const int f  = s >> 6, l = s & 63;
        const int kk = f >> 3, n = f & 7;
        const int k0 = kk * 32 + ((l >> 4) << 3);
        const int cl = (n << 4) + (l & 15);
        union { s16x8 v; unsigned short u[8]; } r;
#pragma unroll
        for (int j = 0; j < 8; ++j)
            r.u[j] = f2bf(w1[(k0 + j) * 128 + cl]);
        *reinterpret_cast<s16x8*>(&w1s[s * 8]) = r.v;
    }
    if (t < 128) b1s[t] = b1[t];

    // ---- w2 fragments + b2 vectors -> LDS (wave 0 only) ----
    if (wid == 0) {
#pragma unroll
        for (int m = 0; m < 4; ++m)
#pragma unroll
            for (int n2 = 0; n2 < 2; ++n2) {
                union { s16x8 v; unsigned short u[8]; } r;
#pragma unroll
                for (int j = 0; j < 4; ++j) {
                    r.u[j]     = f2bf(w2[(m * 16 + rq * 4 + j) * 32 + n2 * 16 + rr]);
                    r.u[4 + j] = f2bf(w2[((m + 4) * 16 + rq * 4 + j) * 32 + n2 * 16 + rr]);
                }
                *reinterpret_cast<s16x8*>(&w2s[((m * 2 + n2) * 64 + lane) * 8]) = r.v;
            }
        *reinterpret_cast<f32x4*>(&b2s[(0 * 64 + lane) * 4]) =
            *reinterpret_cast<const f32x4*>(b2 + rq * 4);
        *reinterpret_cast<f32x4*>(&b2s[(1 * 64 + lane) * 4]) =
            *reinterpret_cast<const f32x4*>(b2 + 16 + rq * 4);
    }

    __syncthreads();

    char* const wsS = xs[wid];                      // src tile: 16 rows x 144 B
    char* const wsD = xs[wid] + 16 * SRC_STRIDE;    // dst tile: 16 rows x 144 B
    char* const wsE = xs[wid] + 32 * SRC_STRIDE;    // edg tile: 16 rows x 80 B

    const int srow  = lane >> 4;          // staging sub-row (src/dst)
    const int scol8 = (lane & 15) * 8;    // staging byte col (src/dst)
    const int erow  = lane >> 3;          // staging sub-row (edge)
    const int ecol8 = (lane & 7) * 8;     // staging byte col (edge)

    for (int tile = blockIdx.x; tile < ntiles; tile += gridDim.x) {
        const size_t row0 = (size_t)tile * 512 + (size_t)wid * 32;

        // ---- issue ALL 20 coalesced loads (rows 0..31) back-to-back ----
        // each instruction = 1024 contiguous B = 8 whole lines, consumed once.
        const float* gsA = src + row0 * 64 + lane * 4;
        const float* gdA = dst + row0 * 64 + lane * 4;
        const float* geA = edg + row0 * 32 + lane * 4;
        const float* gsB = gsA + 16 * 64;
        const float* gdB = gdA + 16 * 64;
        const float* geB = geA + 16 * 32;

        f32x4 sA0, sA1, sA2, sA3, dA0, dA1, dA2, dA3, eA0, eA1;
        f32x4 sB0, sB1, sB2, sB3, dB0, dB1, dB2, dB3, eB0, eB1;
        asm volatile(
            "global_load_dwordx4 %[s0], %[ps], off\n\t"
            "global_load_dwordx4 %[s1], %[ps], off offset:1024\n\t"
            "global_load_dwordx4 %[s2], %[ps], off offset:2048\n\t"
            "global_load_dwordx4 %[s3], %[ps], off offset:3072\n\t"
            "global_load_dwordx4 %[d0], %[pd], off\n\t"
            "global_load_dwordx4 %[d1], %[pd], off offset:1024\n\t"
            "global_load_dwordx4 %[d2], %[pd], off offset:2048\n\t"
            "global_load_dwordx4 %[d3], %[pd], off offset:3072\n\t"
            "global_load_dwordx4 %[e0], %[pe], off\n\t"
            "global_load_dwordx4 %[e1], %[pe], off offset:1024"
            : [s0]"=&v"(sA0), [s1]"=&v"(sA1), [s2]"=&v"(sA2), [s3]"=&v"(sA3),
              [d0]"=&v"(dA0), [d1]"=&v"(dA1), [d2]"=&v"(dA2), [d3]"=&v"(dA3),
              [e0]"=&v"(eA0), [e1]"=&v"(eA1)
            : [ps]"v"(gsA), [pd]"v"(gdA), [pe]"v"(geA));
        asm volatile(
            "global_load_dwordx4 %[s0], %[ps], off\n\t"
            "global_load_dwordx4 %[s1], %[ps], off offset:1024\n\t"
            "global_load_dwordx4 %[s2], %[ps], off offset:2048\n\t"
            "global_load_dwordx4 %[s3], %[ps], off offset:3072\n\t"
            "global_load_dwordx4 %[d0], %[pd], off\n\t"
            "global_load_dwordx4 %[d1], %[pd], off offset:1024\n\t"
            "global_load_dwordx4 %[d2], %[pd], off offset:2048\n\t"
            "global_load_dwordx4 %[d3], %[pd], off offset:3072\n\t"
            "global_load_dwordx4 %[e0], %[pe], off\n\t"
            "global_load_dwordx4 %[e1], %[pe], off offset:1024"
            : [s0]"=&v"(sB0), [s1]"=&v"(sB1), [s2]"=&v"(sB2), [s3]"=&v"(sB3),
              [d0]"=&v"(dB0), [d1]"=&v"(dB1), [d2]"=&v"(dB2), [d3]"=&v"(dB3),
              [e0]"=&v"(eB0), [e1]"=&v"(eB1)
            : [ps]"v"(gsB), [pd]"v"(gdB), [pe]"v"(geB));

        // wait for batch A only (10 newer still outstanding); "+v" ties the
        // wait into the dataflow so consumers can't be hoisted above it.
        asm volatile("s_waitcnt vmcnt(10)"
            : [s0]"+v"(sA0), [s1]"+v"(sA1), [s2]"+v"(sA2), [s3]"+v"(sA3),
              [d0]"+v"(dA0), [d1]"+v"(dA1), [d2]"+v"(dA2), [d3]"+v"(dA3),
              [e0]"+v"(eA0), [e1]"+v"(eA1));

        // ---- stage rows 0..15 + read a0 frags to registers ----
        {
            const f32x4 ls[4] = {sA0, sA1, sA2, sA3};
#pragma unroll
            for (int i = 0; i < 4; ++i) {
                u16x4 p = {f2bf(ls[i].x), f2bf(ls[i].y), f2bf(ls[i].z), f2bf(ls[i].w)};
                *reinterpret_cast<u16x4*>(wsS + (i * 4 + srow) * SRC_STRIDE + scol8) = p;
            }
            const f32x4 ld[4] = {dA0, dA1, dA2, dA3};
#pragma unroll
            for (int i = 0; i < 4; ++i) {
                u16x4 p = {f2bf(ld[i].x), f2bf(ld[i].y), f2bf(ld[i].z), f2bf(ld[i].w)};
                *reinterpret_cast<u16x4*>(wsD + (i * 4 + srow) * SRC_STRIDE + scol8) = p;
            }
            const f32x4 le[2] = {eA0, eA1};
#pragma unroll
            for (int i = 0; i < 2; ++i) {
                u16x4 p = {f2bf(le[i].x), f2bf(le[i].y), f2bf(le[i].z), f2bf(le[i].w)};
                *reinterpret_cast<u16x4*>(wsE + (i * 8 + erow) * EDG_STRIDE + ecol8) = p;
            }
        }
        s16x8 a0f[5], a1f[5];
#pragma unroll
        for (int kk = 0; kk < 5; ++kk) {
            const char* xb; int koff, strd;
            if      (kk == 0) { xb = wsS; koff = 0;  strd = SRC_STRIDE; }
            else if (kk == 1) { xb = wsS; koff = 64; strd = SRC_STRIDE; }
            else if (kk == 2) { xb = wsD; koff = 0;  strd = SRC_STRIDE; }
            else if (kk == 3) { xb = wsD; koff = 64; strd = SRC_STRIDE; }
            else              { xb = wsE; koff = 0;  strd = EDG_STRIDE; }
            a0f[kk] = *reinterpret_cast<const s16x8*>(xb + rr * strd + koff + rq * 16);
        }

        // wait for batch B, then restage rows 16..31 into the SAME buffer.
        // (DS ops are wave-in-order; reads above target the same __shared__
        // object so the compiler preserves read-before-rewrite order.)
        asm volatile("s_waitcnt vmcnt(0)"
            : [s0]"+v"(sB0), [s1]"+v"(sB1), [s2]"+v"(sB2), [s3]"+v"(sB3),
              [d0]"+v"(dB0), [d1]"+v"(dB1), [d2]"+v"(dB2), [d3]"+v"(dB3),
              [e0]"+v"(eB0), [e1]"+v"(eB1));
        {
            const f32x4 ls[4] = {sB0, sB1, sB2, sB3};
#pragma unroll
            for (int i = 0; i < 4; ++i) {
                u16x4 p = {f2bf(ls[i].x), f2bf(ls[i].y), f2bf(ls[i].z), f2bf(ls[i].w)};
                *reinterpret_cast<u16x4*>(wsS + (i * 4 + srow) * SRC_STRIDE + scol8) = p;
            }
            const f32x4 ld[4] = {dB0, dB1, dB2, dB3};
#pragma unroll
            for (int i = 0; i < 4; ++i) {
                u16x4 p = {f2bf(ld[i].x), f2bf(ld[i].y), f2bf(ld[i].z), f2bf(ld[i].w)};
                *reinterpret_cast<u16x4*>(wsD + (i * 4 + srow) * SRC_STRIDE + scol8) = p;
            }
            const f32x4 le[2] = {eB0, eB1};
#pragma unroll
            for (int i = 0; i < 2; ++i) {
                u16x4 p = {f2bf(le[i].x), f2bf(le[i].y), f2bf(le[i].z), f2bf(le[i].w)};
                *reinterpret_cast<u16x4*>(wsE + (i * 8 + erow) * EDG_STRIDE + ecol8) = p;
            }
        }
#pragma unroll
        for (int kk = 0; kk < 5; ++kk) {
            const char* xb; int koff, strd;
            if      (kk == 0) { xb = wsS; koff = 0;  strd = SRC_STRIDE; }
            else if (kk == 1) { xb = wsS; koff = 64; strd = SRC_STRIDE; }
            else if (kk == 2) { xb = wsD; koff = 0;  strd = SRC_STRIDE; }
            else if (kk == 3) { xb = wsD; koff = 64; strd = SRC_STRIDE; }
            else              { xb = wsE; koff = 0;  strd = EDG_STRIDE; }
            a1f[kk] = *reinterpret_cast<const s16x8*>(xb + rr * strd + koff + rq * 16);
        }

        // ---- GEMM1 (swapped): one w1-frag read feeds TWO MFMAs ----
        f32x4 acc0[8], acc1[8];
#pragma unroll
        for (int n = 0; n < 8; ++n) {
            f32x4 b = *reinterpret_cast<const f32x4*>(&b1s[n * 16 + rq * 4]);
            acc0[n] = b;
            acc1[n] = b;
        }
#pragma unroll
        for (int kk = 0; kk < 5; ++kk)
#pragma unroll
            for (int n = 0; n < 8; ++n) {
                s16x8 wv = *reinterpret_cast<const s16x8*>(&w1s[((kk * 8 + n) * 64 + lane) * 8]);
                acc0[n] = __builtin_amdgcn_mfma_f32_16x16x32_bf16(wv, a0f[kk], acc0[n], 0, 0, 0);
                acc1[n] = __builtin_amdgcn_mfma_f32_16x16x32_bf16(wv, a1f[kk], acc1[n], 0, 0, 0);
            }

        // ---- GEMM2 + store per row-frag (R6-verified; w2/b2 from LDS) ----
#pragma unroll
        for (int rf = 0; rf < 2; ++rf) {
            f32x4 acc2[2];
            acc2[0] = *reinterpret_cast<const f32x4*>(&b2s[(0 * 64 + lane) * 4]);
            acc2[1] = *reinterpret_cast<const f32x4*>(&b2s[(1 * 64 + lane) * 4]);

#pragma unroll
            for (int m = 0; m < 4; ++m) {
                union { s16x8 v; unsigned short u[8]; } hh;
#pragma unroll
                for (int j = 0; j < 4; ++j) {
                    hh.u[j]     = f2bf(fmaxf((rf == 0 ? acc0[m][j]     : acc1[m][j]),     0.0f));
                    hh.u[4 + j] = f2bf(fmaxf((rf == 0 ? acc0[m + 4][j] : acc1[m + 4][j]), 0.0f));
                }
                s16x8 w20 = *reinterpret_cast<const s16x8*>(&w2s[((m * 2 + 0) * 64 + lane) * 8]);
                s16x8 w21 = *reinterpret_cast<const s16x8*>(&w2s[((m * 2 + 1) * 64 + lane) * 8]);
                acc2[0] = __builtin_amdgcn_mfma_f32_16x16x32_bf16(w20, hh.v, acc2[0], 0, 0, 0);
                acc2[1] = __builtin_amdgcn_mfma_f32_16x16x32_bf16(w21, hh.v, acc2[1], 0, 0, 0);
            }

            float* po = out + (row0 + rf * 16 + rr) * 32;
            *reinterpret_cast<f32x4*>(po + rq * 4)      = acc2[0];
            *reinterpret_cast<f32x4*>(po + 16 + rq * 4) = acc2[1];
        }
    }
}

// Scalar tail for E % 512 != 0 (not hit for E = 1,600,000; kept for safety)
__global__ void edge_mlp_tail(
    const float* __restrict__ src, const float* __restrict__ dst,
    const float* __restrict__ edg, const float* __restrict__ w1,
    const float* __restrict__ b1, const float* __restrict__ w2,
    const float* __restrict__ b2, float* __restrict__ out,
    long long row0, long long E)
{
    const long long r = row0 + blockIdx.x;
    if (r >= E) return;
    __shared__ float h[128];
    const int t = threadIdx.x;  // 128 threads
    float acc = b1[t];
    for (int k = 0; k < 64; ++k) acc += src[r * 64 + k] * w1[k * 128 + t];
    for (int k = 0; k < 64; ++k) acc += dst[r * 64 + k] * w1[(64 + k) * 128 + t];
    for (int k = 0; k < 32; ++k) acc += edg[r * 32 + k] * w1[(128 + k) * 128 + t];
    h[t] = acc > 0.0f ? acc : 0.0f;
    __syncthreads();
    if (t < 32) {
        float o = b2[t];
        for (int k = 0; k < 128; ++k) o += h[k] * w2[k * 32 + t];
        out[r * 32 + t] = o;
    }
}

extern "C" void kernel_launch(void* const* d_in, const int* in_sizes, int n_in,
                              void* d_out, int out_size, void* d_ws, size_t ws_size,
                              hipStream_t stream)
{
    const float* src = (const float*)d_in[0];
    const float* dst = (const float*)d_in[1];
    const float* edg = (const float*)d_in[2];
    // d_in[3] = u (unused), d_in[4] = batch (unused)
    const float* w1  = (const float*)d_in[5];
    const float* b1  = (const float*)d_in[6];
    const float* w2  = (const float*)d_in[7];
    const float* b2  = (const float*)d_in[8];
    float* out = (float*)d_out;

    const long long E      = (long long)in_sizes[0] / 64;
    const int       ntiles = (int)(E / 512);
    const long long rem    = E - (long long)ntiles * 512;

    if (ntiles > 0) {
        int grid = ntiles < 256 ? ntiles : 256;
        edge_mlp<<<dim3(grid), dim3(1024), 0, stream>>>(
            src, dst, edg, w1, b1, w2, b2, out, ntiles);
    }
    if (rem > 0) {
        edge_mlp_tail<<<dim3((unsigned)rem), dim3(128), 0, stream>>>(
            src, dst, edg, w1, b1, w2, b2, out, (long long)ntiles * 512, E);
    }
}